// Round 9
// baseline (475.858 us; speedup 1.0000x reference)
//
#include <hip/hip_runtime.h>
#include <math.h>

#define BB 256
#define LL 256
#define HH 1024
#define NH 16
#define DD 64
#define SCALE 0.5f
#define LN_EPS 1e-5f
#define NEG_BIG (-3.402823466e38f)

#define FMA4(accv, vq, s)                \
  accv.x = fmaf(vq.x, s, accv.x);       \
  accv.y = fmaf(vq.y, s, accv.y);       \
  accv.z = fmaf(vq.z, s, accv.z);       \
  accv.w = fmaf(vq.w, s, accv.w);

// ---------------------------------------------------------------------------
// t_tr: tiled 64x64 transpose with strides, z-planes for 3D permutes.
// ---------------------------------------------------------------------------
__global__ __launch_bounds__(256) void t_tr(const float* __restrict__ in,
                                            float* __restrict__ out, int inRS,
                                            int outRS, int inPlane,
                                            int outPlane) {
  __shared__ float lds[64][68];
  const float* ip = in + (size_t)blockIdx.z * inPlane;
  float* op = out + (size_t)blockIdx.z * outPlane;
  const int rt = blockIdx.y, ct = blockIdx.x;
  const int lr = threadIdx.x >> 4;
  const int lc = (threadIdx.x & 15) * 4;
#pragma unroll
  for (int p = 0; p < 4; p++) {
    float4 v = *(const float4*)(ip + (size_t)(rt * 64 + p * 16 + lr) * inRS +
                                ct * 64 + lc);
    *(float4*)(&lds[p * 16 + lr][lc]) = v;
  }
  __syncthreads();
#pragma unroll
  for (int p = 0; p < 4; p++) {
    float4 v = make_float4(lds[lc + 0][p * 16 + lr], lds[lc + 1][p * 16 + lr],
                           lds[lc + 2][p * 16 + lr], lds[lc + 3][p * 16 + lr]);
    *(float4*)(op + (size_t)(ct * 64 + p * 16 + lr) * outRS + rt * 64 + lc) = v;
  }
}

// ---------------------------------------------------------------------------
// K1: qT[j][b] = bq[j] + sum_i query[b][i]*Wq[j][i]   (verified)
// ---------------------------------------------------------------------------
__global__ __launch_bounds__(256) void k1_qproj(const float* __restrict__ Wq,
                                                const float* __restrict__ qTT,
                                                const float* __restrict__ bq,
                                                float* __restrict__ qT) {
  __shared__ float smem[10240];
  const int jt = blockIdx.x;
  const int boff = blockIdx.y * 8;
  const int t = threadIdx.x;
  const int g = __builtin_amdgcn_readfirstlane(t >> 6);
  const int ln = t & 63;
  float* kw = smem + g * 2560;
  const float* Wb = Wq + (size_t)(jt * 64) * HH;
  const int srow = ln >> 2, sc = ln & 3;

  float acc[8];
#pragma unroll
  for (int c = 0; c < 8; c++) acc[c] = 0.f;
  float4 pf[4];
#pragma unroll
  for (int p = 0; p < 4; p++)
    pf[p] = *(const float4*)(Wb + (size_t)(p * 16 + srow) * HH + g * 16 + sc * 4);
  int buf = 0;
  for (int T = 0; T < 16; T++) {
    float* kb = kw + buf * 1280;
#pragma unroll
    for (int p = 0; p < 4; p++)
      *(float4*)(kb + ((p * 16 + srow) * 5 + sc) * 4) = pf[p];
    if (T < 15) {
      const int off = (T + 1) * 64 + g * 16 + sc * 4;
#pragma unroll
      for (int p = 0; p < 4; p++)
        pf[p] = *(const float4*)(Wb + (size_t)(p * 16 + srow) * HH + off);
    }
    const int i0 = T * 64 + g * 16;
#pragma unroll
    for (int u = 0; u < 4; u++) {
      float4 kv = *(const float4*)(kb + (ln * 5 + u) * 4);
      const float* q0 = qTT + (size_t)(i0 + u * 4 + 0) * BB + boff;
      const float* q1 = qTT + (size_t)(i0 + u * 4 + 1) * BB + boff;
      const float* q2 = qTT + (size_t)(i0 + u * 4 + 2) * BB + boff;
      const float* q3 = qTT + (size_t)(i0 + u * 4 + 3) * BB + boff;
#pragma unroll
      for (int c = 0; c < 8; c++) {
        acc[c] = fmaf(kv.x, q0[c], acc[c]);
        acc[c] = fmaf(kv.y, q1[c], acc[c]);
        acc[c] = fmaf(kv.z, q2[c], acc[c]);
        acc[c] = fmaf(kv.w, q3[c], acc[c]);
      }
    }
    buf ^= 1;
  }
  __syncthreads();
  float* part = smem;
  *(float4*)(part + g * 768 + ln * 12 + 0) =
      make_float4(acc[0], acc[1], acc[2], acc[3]);
  *(float4*)(part + g * 768 + ln * 12 + 4) =
      make_float4(acc[4], acc[5], acc[6], acc[7]);
  __syncthreads();
  const int j = t & 63, c0 = (t >> 6) * 2;
  float v0 = 0.f, v1 = 0.f;
#pragma unroll
  for (int g2 = 0; g2 < 4; g2++) {
    v0 += part[g2 * 768 + j * 12 + c0];
    v1 += part[g2 * 768 + j * 12 + c0 + 1];
  }
  const int jg = jt * 64 + j;
  const float bias = bq[jg];
  *(float2*)(qT + (size_t)jg * BB + boff + c0) =
      make_float2(v0 + bias, v1 + bias);
}

// ---------------------------------------------------------------------------
// K2: qkT[b][h][i] = SCALE * sum_d qT[h*64+d][b] * Wk[h*64+d][i]   (verified)
// ---------------------------------------------------------------------------
__global__ __launch_bounds__(256) void k2_qk(const float* __restrict__ qT,
                                             const float* __restrict__ Wk,
                                             float* __restrict__ qkT) {
  const int h = blockIdx.y;
  const int it = blockIdx.x;
  const int il = threadIdx.x & 63;
  const int bs = __builtin_amdgcn_readfirstlane(threadIdx.x >> 6);
  const int i = it * 64 + il;
  const int boff = blockIdx.z * 64 + bs * 16;
  float acc[16];
#pragma unroll
  for (int k = 0; k < 16; k++) acc[k] = 0.f;
#pragma unroll 2
  for (int d = 0; d < DD; d++) {
    float wv = Wk[(size_t)(h * DD + d) * HH + i];
    const float* qrow = qT + (h * DD + d) * BB + boff;  // wave-uniform
#pragma unroll
    for (int k = 0; k < 16; k++) acc[k] = fmaf(qrow[k], wv, acc[k]);
  }
#pragma unroll
  for (int k = 0; k < 16; k++)
    qkT[(size_t)((boff + k) * NH + h) * HH + i] = SCALE * acc[k];
}

// ---------------------------------------------------------------------------
// K2b (verified R5): qkT[b][h][i] -> qkR[b][i>>2][16h][i&3].
// ---------------------------------------------------------------------------
__global__ __launch_bounds__(256) void k2b_relayout(
    const float* __restrict__ qkT, float* __restrict__ qkR) {
  __shared__ float lds[16][268];
  const int b = blockIdx.y, seg = blockIdx.x;
  const int t = threadIdx.x;
  const int row = t >> 4, l16 = t & 15;
  const float* src = qkT + (size_t)b * 16384 + row * HH + seg * 256 + l16 * 16;
#pragma unroll
  for (int p = 0; p < 4; p++)
    *(float4*)(&lds[row][l16 * 16 + p * 4]) = *(const float4*)(src + p * 4);
  __syncthreads();
  const int c = t & 63;    // h*4 + i3
  const int i4g = t >> 6;  // 0..3
  const int h = c >> 2, i3 = c & 3;
  float* dst = qkR + (size_t)b * 16384 + seg * 4096;
#pragma unroll
  for (int jj = 0; jj < 16; jj++) {
    const int i4l = i4g * 16 + jj;
    dst[i4l * 64 + c] = lds[h][i4l * 4 + i3];
  }
}

// ---------------------------------------------------------------------------
// K3a: scores[b][h][l] = mask ? NEG_BIG : sum_i key[b][l][i]*qk[b][h][i]
// R8 structure (register-blocked 4l x 4h, block-staged dbuf key tile, qkR
// b128 fragments, shfl K-reduce) with the ONE fix: the epilogue previously
// did acc[g4][h] with RUNTIME g4 -> whole acc array demoted to scratch
// (VGPR=68, 167 MB ghost HBM writes).  Now: static-index cndmask selects.
// ---------------------------------------------------------------------------
__global__ __launch_bounds__(256) void k3a_scores(
    const float* __restrict__ key, const int* __restrict__ mask,
    const float* __restrict__ qkR, float* __restrict__ scoresT) {
  __shared__ float klds[2][64 * 68];
  __shared__ float qlds[2][1024];
  const int b = blockIdx.y;
  const int lt = blockIdx.x;
  const int t = threadIdx.x;
  const int g = __builtin_amdgcn_readfirstlane(t >> 6);  // h-quad
  const int ln = t & 63;
  const int m15 = ln & 15;       // row-group
  const int g4 = ln >> 4;        // i-quarter within chunk
  const int srow = t >> 4;       // staging row 0..15 (+16p)
  const int sc4 = (t & 15) * 4;  // staging i-offset

  const float* keyb = key + ((size_t)(b * LL + lt * 64)) * HH;
  const float* qkb = qkR + (size_t)b * 16384;

  float acc[4][4];
#pragma unroll
  for (int r = 0; r < 4; r++)
#pragma unroll
    for (int h = 0; h < 4; h++) acc[r][h] = 0.f;

  // prologue: chunk 0 into regs
  float4 kf[4];
#pragma unroll
  for (int p = 0; p < 4; p++)
    kf[p] = *(const float4*)(keyb + (size_t)(srow + 16 * p) * HH + sc4);
  float4 qf = *(const float4*)(qkb + t * 4);

  for (int c = 0; c < 16; c++) {
    float* kb = klds[c & 1];
    float* qb = qlds[c & 1];
#pragma unroll
    for (int p = 0; p < 4; p++)
      *(float4*)(kb + (srow + 16 * p) * 68 + sc4) = kf[p];
    *(float4*)(qb + t * 4) = qf;
    if (c < 15) {
      const int ioff = 64 * (c + 1);
#pragma unroll
      for (int p = 0; p < 4; p++)
        kf[p] = *(const float4*)(keyb + (size_t)(srow + 16 * p) * HH + ioff + sc4);
      qf = *(const float4*)(qkb + 1024 * (c + 1) + t * 4);
    }
    __syncthreads();
#pragma unroll
    for (int iq = 0; iq < 4; iq++) {
      const int iqf = g4 * 4 + iq;               // i-quad unit 0..15
      const float* qu = qb + iqf * 64 + g * 16;  // [4h][4i] fragment
      float4 q0 = *(const float4*)(qu + 0);
      float4 q1 = *(const float4*)(qu + 4);
      float4 q2 = *(const float4*)(qu + 8);
      float4 q3 = *(const float4*)(qu + 12);
      const int il = g4 * 16 + iq * 4;           // i within chunk
#pragma unroll
      for (int r = 0; r < 4; r++) {
        float4 kv = *(const float4*)(kb + (m15 + 16 * r) * 68 + il);
        acc[r][0] = fmaf(kv.x, q0.x, acc[r][0]);
        acc[r][0] = fmaf(kv.y, q0.y, acc[r][0]);
        acc[r][0] = fmaf(kv.z, q0.z, acc[r][0]);
        acc[r][0] = fmaf(kv.w, q0.w, acc[r][0]);
        acc[r][1] = fmaf(kv.x, q1.x, acc[r][1]);
        acc[r][1] = fmaf(kv.y, q1.y, acc[r][1]);
        acc[r][1] = fmaf(kv.z, q1.z, acc[r][1]);
        acc[r][1] = fmaf(kv.w, q1.w, acc[r][1]);
        acc[r][2] = fmaf(kv.x, q2.x, acc[r][2]);
        acc[r][2] = fmaf(kv.y, q2.y, acc[r][2]);
        acc[r][2] = fmaf(kv.z, q2.z, acc[r][2]);
        acc[r][2] = fmaf(kv.w, q2.w, acc[r][2]);
        acc[r][3] = fmaf(kv.x, q3.x, acc[r][3]);
        acc[r][3] = fmaf(kv.y, q3.y, acc[r][3]);
        acc[r][3] = fmaf(kv.z, q3.z, acc[r][3]);
        acc[r][3] = fmaf(kv.w, q3.w, acc[r][3]);
      }
    }
  }

  // K-reduce across the 4 i-quarter lane groups (xor 16, 32)
#pragma unroll
  for (int r = 0; r < 4; r++)
#pragma unroll
    for (int h = 0; h < 4; h++) {
      acc[r][h] += __shfl_xor(acc[r][h], 16);
      acc[r][h] += __shfl_xor(acc[r][h], 32);
    }

  // lane group g4 outputs row-set r == g4.  STATIC indices only (rule #20:
  // acc[g4][h] with runtime g4 sent the whole array to scratch in R8).
  float o0 = acc[0][0], o1 = acc[0][1], o2 = acc[0][2], o3 = acc[0][3];
  if (g4 == 1) { o0 = acc[1][0]; o1 = acc[1][1]; o2 = acc[1][2]; o3 = acc[1][3]; }
  if (g4 == 2) { o0 = acc[2][0]; o1 = acc[2][1]; o2 = acc[2][2]; o3 = acc[2][3]; }
  if (g4 == 3) { o0 = acc[3][0]; o1 = acc[3][1]; o2 = acc[3][2]; o3 = acc[3][3]; }

  const int l = lt * 64 + 16 * g4 + m15;
  const int mk = mask[b * LL + l];
  if (mk) { o0 = NEG_BIG; o1 = NEG_BIG; o2 = NEG_BIG; o3 = NEG_BIG; }
  scoresT[((size_t)(b * NH + g * 4 + 0)) * LL + l] = o0;
  scoresT[((size_t)(b * NH + g * 4 + 1)) * LL + l] = o1;
  scoresT[((size_t)(b * NH + g * 4 + 2)) * LL + l] = o2;
  scoresT[((size_t)(b * NH + g * 4 + 3)) * LL + l] = o3;
}

// ---------------------------------------------------------------------------
// K3b: in-place softmax over attn[(b*16+h)][256].   (verified)
// ---------------------------------------------------------------------------
__global__ __launch_bounds__(256) void k3b_softmax(float* __restrict__ attn) {
  const int r = blockIdx.x * 4 + (threadIdx.x >> 6);
  const int lane = threadIdx.x & 63;
  float* rowp = attn + (size_t)r * LL;
  float4 s = *(const float4*)(rowp + lane * 4);
  float m = fmaxf(fmaxf(s.x, s.y), fmaxf(s.z, s.w));
#pragma unroll
  for (int off = 32; off >= 1; off >>= 1) m = fmaxf(m, __shfl_xor(m, off));
  float ex = __expf(s.x - m), ey = __expf(s.y - m), ez = __expf(s.z - m),
        ew = __expf(s.w - m);
  float e = ex + ey + ez + ew;
#pragma unroll
  for (int off = 32; off >= 1; off >>= 1) e += __shfl_xor(e, off);
  float inv = 1.0f / e;
  *(float4*)(rowp + lane * 4) = make_float4(ex * inv, ey * inv, ez * inv, ew * inv);
}

// ---------------------------------------------------------------------------
// K3c: vbar[b][h][d] = sum_l attn[b][h][l] * value[b][l][d]
// (R8 version; audited: all register arrays statically indexed.)
// ---------------------------------------------------------------------------
__global__ __launch_bounds__(256) void k3c_vbar(
    const float* __restrict__ value, const float* __restrict__ attn,
    float* __restrict__ vbar) {
  __shared__ float alds[4096];  // [16 h][256 l]
  const int b = blockIdx.y;
  const int dt = blockIdx.x;
  const int t = threadIdx.x;
  const int g = __builtin_amdgcn_readfirstlane(t >> 6);
  const int ln = t & 63;
  const float* ab = attn + (size_t)b * 4096;
#pragma unroll
  for (int j = 0; j < 4; j++)
    *(float4*)(alds + j * 1024 + t * 4) = *(const float4*)(ab + j * 1024 + t * 4);
  __syncthreads();

  const int d0 = dt * 256 + ln * 4;
  const float* valb = value + (size_t)b * LL * HH + d0;
  const float* aw = alds + g * 4 * 256;  // wave's 4 h rows

  float4 ac0 = make_float4(0.f, 0.f, 0.f, 0.f);
  float4 ac1 = ac0, ac2 = ac0, ac3 = ac0;

  float4 vf0 = *(const float4*)(valb + (size_t)0 * HH);
  float4 vf1 = *(const float4*)(valb + (size_t)1 * HH);
  float4 vf2 = *(const float4*)(valb + (size_t)2 * HH);
  float4 vf3 = *(const float4*)(valb + (size_t)3 * HH);

#pragma unroll 4
  for (int lq = 0; lq < 64; lq++) {
    float4 v0 = vf0, v1 = vf1, v2 = vf2, v3 = vf3;
    if (lq < 63) {
      vf0 = *(const float4*)(valb + (size_t)((lq + 1) * 4 + 0) * HH);
      vf1 = *(const float4*)(valb + (size_t)((lq + 1) * 4 + 1) * HH);
      vf2 = *(const float4*)(valb + (size_t)((lq + 1) * 4 + 2) * HH);
      vf3 = *(const float4*)(valb + (size_t)((lq + 1) * 4 + 3) * HH);
    }
    float4 a0 = *(const float4*)(aw + 0 * 256 + lq * 4);
    float4 a1 = *(const float4*)(aw + 1 * 256 + lq * 4);
    float4 a2 = *(const float4*)(aw + 2 * 256 + lq * 4);
    float4 a3 = *(const float4*)(aw + 3 * 256 + lq * 4);
    FMA4(ac0, v0, a0.x); FMA4(ac0, v1, a0.y); FMA4(ac0, v2, a0.z); FMA4(ac0, v3, a0.w);
    FMA4(ac1, v0, a1.x); FMA4(ac1, v1, a1.y); FMA4(ac1, v2, a1.z); FMA4(ac1, v3, a1.w);
    FMA4(ac2, v0, a2.x); FMA4(ac2, v1, a2.y); FMA4(ac2, v2, a2.z); FMA4(ac2, v3, a2.w);
    FMA4(ac3, v0, a3.x); FMA4(ac3, v1, a3.y); FMA4(ac3, v2, a3.z); FMA4(ac3, v3, a3.w);
  }
  float* vb = vbar + ((size_t)(b * NH + g * 4)) * HH + d0;
  *(float4*)(vb + 0 * HH) = ac0;
  *(float4*)(vb + 1 * HH) = ac1;
  *(float4*)(vb + 2 * HH) = ac2;
  *(float4*)(vb + 3 * HH) = ac3;
}

// ---------------------------------------------------------------------------
// K4: ctxT[j][b] = bv[j] + sum_i vbar[b][j>>6][i] * Wv[j][i]   (verified)
// ---------------------------------------------------------------------------
__global__ __launch_bounds__(256) void k4_ctx(const float* __restrict__ Wv,
                                              const float* __restrict__ vbarT,
                                              const float* __restrict__ bv,
                                              float* __restrict__ ctxT) {
  __shared__ float smem[10240];
  const int jt = blockIdx.x;
  const int boff = blockIdx.y * 8;
  const int t = threadIdx.x;
  const int g = __builtin_amdgcn_readfirstlane(t >> 6);
  const int ln = t & 63;
  float* kw = smem + g * 2560;
  const float* Wb = Wv + (size_t)(jt * 64) * HH;
  const float* vt = vbarT + (size_t)jt * HH * BB;
  const int srow = ln >> 2, sc = ln & 3;

  float acc[8];
#pragma unroll
  for (int c = 0; c < 8; c++) acc[c] = 0.f;
  float4 pf[4];
#pragma unroll
  for (int p = 0; p < 4; p++)
    pf[p] = *(const float4*)(Wb + (size_t)(p * 16 + srow) * HH + g * 16 + sc * 4);
  int buf = 0;
  for (int T = 0; T < 16; T++) {
    float* kb = kw + buf * 1280;
#pragma unroll
    for (int p = 0; p < 4; p++)
      *(float4*)(kb + ((p * 16 + srow) * 5 + sc) * 4) = pf[p];
    if (T < 15) {
      const int off = (T + 1) * 64 + g * 16 + sc * 4;
#pragma unroll
      for (int p = 0; p < 4; p++)
        pf[p] = *(const float4*)(Wb + (size_t)(p * 16 + srow) * HH + off);
    }
    const int i0 = T * 64 + g * 16;
#pragma unroll
    for (int u = 0; u < 4; u++) {
      float4 kv = *(const float4*)(kb + (ln * 5 + u) * 4);
      const float* q0 = vt + (size_t)(i0 + u * 4 + 0) * BB + boff;
      const float* q1 = vt + (size_t)(i0 + u * 4 + 1) * BB + boff;
      const float* q2 = vt + (size_t)(i0 + u * 4 + 2) * BB + boff;
      const float* q3 = vt + (size_t)(i0 + u * 4 + 3) * BB + boff;
#pragma unroll
      for (int c = 0; c < 8; c++) {
        acc[c] = fmaf(kv.x, q0[c], acc[c]);
        acc[c] = fmaf(kv.y, q1[c], acc[c]);
        acc[c] = fmaf(kv.z, q2[c], acc[c]);
        acc[c] = fmaf(kv.w, q3[c], acc[c]);
      }
    }
    buf ^= 1;
  }
  __syncthreads();
  float* part = smem;
  *(float4*)(part + g * 768 + ln * 12 + 0) =
      make_float4(acc[0], acc[1], acc[2], acc[3]);
  *(float4*)(part + g * 768 + ln * 12 + 4) =
      make_float4(acc[4], acc[5], acc[6], acc[7]);
  __syncthreads();
  const int j = t & 63, c0 = (t >> 6) * 2;
  float v0 = 0.f, v1 = 0.f;
#pragma unroll
  for (int g2 = 0; g2 < 4; g2++) {
    v0 += part[g2 * 768 + j * 12 + c0];
    v1 += part[g2 * 768 + j * 12 + c0 + 1];
  }
  const int jg = jt * 64 + j;
  const float bias = bv[jg];
  *(float2*)(ctxT + (size_t)jg * BB + boff + c0) =
      make_float2(v0 + bias, v1 + bias);
}

// ---------------------------------------------------------------------------
// K5: xws[b][j] = query[b][j] + bf[j] + sum_i ctxT[i][b] * Wf[j][i]  (verified)
// ---------------------------------------------------------------------------
__global__ __launch_bounds__(256) void k5_outproj(
    const float* __restrict__ Wf, const float* __restrict__ ctxT,
    const float* __restrict__ bf, const float* __restrict__ query,
    float* __restrict__ xws) {
  __shared__ float smem[10240];
  const int jt = blockIdx.x;
  const int boff = blockIdx.y * 8;
  const int t = threadIdx.x;
  const int g = __builtin_amdgcn_readfirstlane(t >> 6);
  const int ln = t & 63;
  float* kw = smem + g * 2560;
  const float* Wb = Wf + (size_t)(jt * 64) * HH;
  const int srow = ln >> 2, sc = ln & 3;

  float acc[8];
#pragma unroll
  for (int c = 0; c < 8; c++) acc[c] = 0.f;
  float4 pf[4];
#pragma unroll
  for (int p = 0; p < 4; p++)
    pf[p] = *(const float4*)(Wb + (size_t)(p * 16 + srow) * HH + g * 16 + sc * 4);
  int buf = 0;
  for (int T = 0; T < 16; T++) {
    float* kb = kw + buf * 1280;
#pragma unroll
    for (int p = 0; p < 4; p++)
      *(float4*)(kb + ((p * 16 + srow) * 5 + sc) * 4) = pf[p];
    if (T < 15) {
      const int off = (T + 1) * 64 + g * 16 + sc * 4;
#pragma unroll
      for (int p = 0; p < 4; p++)
        pf[p] = *(const float4*)(Wb + (size_t)(p * 16 + srow) * HH + off);
    }
    const int i0 = T * 64 + g * 16;
#pragma unroll
    for (int u = 0; u < 4; u++) {
      float4 kv = *(const float4*)(kb + (ln * 5 + u) * 4);
      const float* q0 = ctxT + (size_t)(i0 + u * 4 + 0) * BB + boff;
      const float* q1 = ctxT + (size_t)(i0 + u * 4 + 1) * BB + boff;
      const float* q2 = ctxT + (size_t)(i0 + u * 4 + 2) * BB + boff;
      const float* q3 = ctxT + (size_t)(i0 + u * 4 + 3) * BB + boff;
#pragma unroll
      for (int c = 0; c < 8; c++) {
        acc[c] = fmaf(kv.x, q0[c], acc[c]);
        acc[c] = fmaf(kv.y, q1[c], acc[c]);
        acc[c] = fmaf(kv.z, q2[c], acc[c]);
        acc[c] = fmaf(kv.w, q3[c], acc[c]);
      }
    }
    buf ^= 1;
  }
  __syncthreads();
  float* part = smem;
  *(float4*)(part + g * 768 + ln * 12 + 0) =
      make_float4(acc[0], acc[1], acc[2], acc[3]);
  *(float4*)(part + g * 768 + ln * 12 + 4) =
      make_float4(acc[4], acc[5], acc[6], acc[7]);
  __syncthreads();
  const int j = t & 63, c0 = (t >> 6) * 2;
  float v0 = 0.f, v1 = 0.f;
#pragma unroll
  for (int g2 = 0; g2 < 4; g2++) {
    v0 += part[g2 * 768 + j * 12 + c0];
    v1 += part[g2 * 768 + j * 12 + c0 + 1];
  }
  const int jg = jt * 64 + j;
  const float bias = bf[jg];
  const int b0 = boff + c0;
  xws[(size_t)b0 * HH + jg] = v0 + bias + query[(size_t)b0 * HH + jg];
  xws[(size_t)(b0 + 1) * HH + jg] = v1 + bias + query[(size_t)(b0 + 1) * HH + jg];
}

// ---------------------------------------------------------------------------
// K6: LayerNorm over H, two-pass (exact), block per b.   (verified)
// ---------------------------------------------------------------------------
__global__ __launch_bounds__(256) void k6_ln(const float* __restrict__ xws,
                                             const float* __restrict__ gamma,
                                             const float* __restrict__ beta,
                                             float* __restrict__ out0) {
  __shared__ float rb[8];
  const int b = blockIdx.x, t = threadIdx.x;
  float4 v = *(const float4*)(xws + (size_t)b * HH + 4 * t);
  float s = v.x + v.y + v.z + v.w;
#pragma unroll
  for (int off = 32; off >= 1; off >>= 1) s += __shfl_xor(s, off);
  if ((t & 63) == 0) rb[t >> 6] = s;
  __syncthreads();
  float mu = (rb[0] + rb[1] + rb[2] + rb[3]) * (1.0f / HH);
  float dx = v.x - mu, dy = v.y - mu, dz = v.z - mu, dw = v.w - mu;
  float q = dx * dx + dy * dy + dz * dz + dw * dw;
#pragma unroll
  for (int off = 32; off >= 1; off >>= 1) q += __shfl_xor(q, off);
  if ((t & 63) == 0) rb[4 + (t >> 6)] = q;
  __syncthreads();
  float var = (rb[4] + rb[5] + rb[6] + rb[7]) * (1.0f / HH);
  float rs = rsqrtf(var + LN_EPS);
  float4 gm = *(const float4*)(gamma + 4 * t);
  float4 bt = *(const float4*)(beta + 4 * t);
  float4 o;
  o.x = dx * rs * gm.x + bt.x;
  o.y = dy * rs * gm.y + bt.y;
  o.z = dz * rs * gm.z + bt.z;
  o.w = dw * rs * gm.w + bt.w;
  *(float4*)(out0 + (size_t)b * HH + 4 * t) = o;
}

extern "C" void kernel_launch(void* const* d_in, const int* in_sizes, int n_in,
                              void* d_out, int out_size, void* d_ws,
                              size_t ws_size, hipStream_t stream) {
  (void)in_sizes; (void)n_in; (void)out_size; (void)ws_size;
  const float* key = (const float*)d_in[0];
  const float* value = (const float*)d_in[1];
  const float* query = (const float*)d_in[2];
  const int* mask = (const int*)d_in[3];
  const float* Wq = (const float*)d_in[4];
  const float* bq = (const float*)d_in[5];
  const float* Wk = (const float*)d_in[6];
  // d_in[7] = bk: softmax-invariant, dropped
  const float* Wv = (const float*)d_in[8];
  const float* bv = (const float*)d_in[9];
  const float* Wf = (const float*)d_in[10];
  const float* bf = (const float*)d_in[11];
  const float* gamma = (const float*)d_in[12];
  const float* beta = (const float*)d_in[13];

  float* out0 = (float*)d_out;      // (B,1,H)
  float* attnOut = out0 + BB * HH;  // (B*NH,1,L): scores -> softmax in place

  // ws lifetimes: qT dead after k2 (ctxT reuses); qTT dead after k1 (xws
  // reuses); qkT dead after k2b (vbar reuses); qkR dead after k3a.
  char* ws = (char*)d_ws;
  float* qT = (float*)(ws);                  //  1 MB [j][b]
  float* qTT = (float*)(ws + (1 << 20));     //  1 MB [i][b]
  float* qkT = (float*)(ws + (2 << 20));     // 16 MB [b][h][i]
  float* qkR = (float*)(ws + (18 << 20));    // 16 MB [b][i4][16h][i3]
  float* vbar = (float*)(ws + (2 << 20));    // 16 MB [b][h][i] (over qkT)
  float* vbarT = (float*)(ws + (34 << 20));  // 16 MB [h][i][b]
  float* ctxT = (float*)(ws);                //  1 MB [j][b]   (over qT)
  float* xws = (float*)(ws + (1 << 20));     //  1 MB [b][j]   (over qTT)

  t_tr<<<dim3(16, 4, 1), 256, 0, stream>>>(query, qTT, HH, BB, 0, 0);
  k1_qproj<<<dim3(16, 32), 256, 0, stream>>>(Wq, qTT, bq, qT);
  k2_qk<<<dim3(16, 16, 4), 256, 0, stream>>>(qT, Wk, qkT);
  k2b_relayout<<<dim3(4, 256), 256, 0, stream>>>(qkT, qkR);
  k3a_scores<<<dim3(4, 256), 256, 0, stream>>>(key, mask, qkR, attnOut);
  k3b_softmax<<<dim3(1024), 256, 0, stream>>>(attnOut);
  k3c_vbar<<<dim3(4, 256), 256, 0, stream>>>(value, attnOut, vbar);
  t_tr<<<dim3(16, 4, 16), 256, 0, stream>>>(vbar, vbarT, NH * HH, BB, HH,
                                            HH * BB);
  k4_ctx<<<dim3(16, 32), 256, 0, stream>>>(Wv, vbarT, bv, ctxT);
  k5_outproj<<<dim3(16, 32), 256, 0, stream>>>(Wf, ctxT, bf, query, xws);
  k6_ln<<<dim3(256), 256, 0, stream>>>(xws, gamma, beta, out0);
}

// Round 10
// 381.075 us; speedup vs baseline: 1.2487x; 1.2487x over previous
//
#include <hip/hip_runtime.h>
#include <math.h>

#define BB 256
#define LL 256
#define HH 1024
#define NH 16
#define DD 64
#define SCALE 0.5f
#define LN_EPS 1e-5f
#define NEG_BIG (-3.402823466e38f)

#define FMA4(accv, vq, s)                \
  accv.x = fmaf(vq.x, s, accv.x);       \
  accv.y = fmaf(vq.y, s, accv.y);       \
  accv.z = fmaf(vq.z, s, accv.z);       \
  accv.w = fmaf(vq.w, s, accv.w);

// Async global->LDS, 16B per lane.  LDS dest must be (wave-uniform base +
// lane*16); global src may be fully per-lane (guide §5 / m173).
__device__ __forceinline__ void gl_lds16(const float* gsrc, float* ldst) {
  __builtin_amdgcn_global_load_lds(
      (const __attribute__((address_space(1))) unsigned int*)gsrc,
      (__attribute__((address_space(3))) unsigned int*)ldst, 16, 0, 0);
}

// ---------------------------------------------------------------------------
// t_tr: tiled 64x64 transpose with strides, z-planes for 3D permutes.
// ---------------------------------------------------------------------------
__global__ __launch_bounds__(256) void t_tr(const float* __restrict__ in,
                                            float* __restrict__ out, int inRS,
                                            int outRS, int inPlane,
                                            int outPlane) {
  __shared__ float lds[64][68];
  const float* ip = in + (size_t)blockIdx.z * inPlane;
  float* op = out + (size_t)blockIdx.z * outPlane;
  const int rt = blockIdx.y, ct = blockIdx.x;
  const int lr = threadIdx.x >> 4;
  const int lc = (threadIdx.x & 15) * 4;
#pragma unroll
  for (int p = 0; p < 4; p++) {
    float4 v = *(const float4*)(ip + (size_t)(rt * 64 + p * 16 + lr) * inRS +
                                ct * 64 + lc);
    *(float4*)(&lds[p * 16 + lr][lc]) = v;
  }
  __syncthreads();
#pragma unroll
  for (int p = 0; p < 4; p++) {
    float4 v = make_float4(lds[lc + 0][p * 16 + lr], lds[lc + 1][p * 16 + lr],
                           lds[lc + 2][p * 16 + lr], lds[lc + 3][p * 16 + lr]);
    *(float4*)(op + (size_t)(ct * 64 + p * 16 + lr) * outRS + rt * 64 + lc) = v;
  }
}

// ---------------------------------------------------------------------------
// K1: qT[j][b] = bq[j] + sum_i query[b][i]*Wq[j][i]   (verified)
// ---------------------------------------------------------------------------
__global__ __launch_bounds__(256) void k1_qproj(const float* __restrict__ Wq,
                                                const float* __restrict__ qTT,
                                                const float* __restrict__ bq,
                                                float* __restrict__ qT) {
  __shared__ float smem[10240];
  const int jt = blockIdx.x;
  const int boff = blockIdx.y * 8;
  const int t = threadIdx.x;
  const int g = __builtin_amdgcn_readfirstlane(t >> 6);
  const int ln = t & 63;
  float* kw = smem + g * 2560;
  const float* Wb = Wq + (size_t)(jt * 64) * HH;
  const int srow = ln >> 2, sc = ln & 3;

  float acc[8];
#pragma unroll
  for (int c = 0; c < 8; c++) acc[c] = 0.f;
  float4 pf[4];
#pragma unroll
  for (int p = 0; p < 4; p++)
    pf[p] = *(const float4*)(Wb + (size_t)(p * 16 + srow) * HH + g * 16 + sc * 4);
  int buf = 0;
  for (int T = 0; T < 16; T++) {
    float* kb = kw + buf * 1280;
#pragma unroll
    for (int p = 0; p < 4; p++)
      *(float4*)(kb + ((p * 16 + srow) * 5 + sc) * 4) = pf[p];
    if (T < 15) {
      const int off = (T + 1) * 64 + g * 16 + sc * 4;
#pragma unroll
      for (int p = 0; p < 4; p++)
        pf[p] = *(const float4*)(Wb + (size_t)(p * 16 + srow) * HH + off);
    }
    const int i0 = T * 64 + g * 16;
#pragma unroll
    for (int u = 0; u < 4; u++) {
      float4 kv = *(const float4*)(kb + (ln * 5 + u) * 4);
      const float* q0 = qTT + (size_t)(i0 + u * 4 + 0) * BB + boff;
      const float* q1 = qTT + (size_t)(i0 + u * 4 + 1) * BB + boff;
      const float* q2 = qTT + (size_t)(i0 + u * 4 + 2) * BB + boff;
      const float* q3 = qTT + (size_t)(i0 + u * 4 + 3) * BB + boff;
#pragma unroll
      for (int c = 0; c < 8; c++) {
        acc[c] = fmaf(kv.x, q0[c], acc[c]);
        acc[c] = fmaf(kv.y, q1[c], acc[c]);
        acc[c] = fmaf(kv.z, q2[c], acc[c]);
        acc[c] = fmaf(kv.w, q3[c], acc[c]);
      }
    }
    buf ^= 1;
  }
  __syncthreads();
  float* part = smem;
  *(float4*)(part + g * 768 + ln * 12 + 0) =
      make_float4(acc[0], acc[1], acc[2], acc[3]);
  *(float4*)(part + g * 768 + ln * 12 + 4) =
      make_float4(acc[4], acc[5], acc[6], acc[7]);
  __syncthreads();
  const int j = t & 63, c0 = (t >> 6) * 2;
  float v0 = 0.f, v1 = 0.f;
#pragma unroll
  for (int g2 = 0; g2 < 4; g2++) {
    v0 += part[g2 * 768 + j * 12 + c0];
    v1 += part[g2 * 768 + j * 12 + c0 + 1];
  }
  const int jg = jt * 64 + j;
  const float bias = bq[jg];
  *(float2*)(qT + (size_t)jg * BB + boff + c0) =
      make_float2(v0 + bias, v1 + bias);
}

// ---------------------------------------------------------------------------
// K2: qkT[b][h][i] = SCALE * sum_d qT[h*64+d][b] * Wk[h*64+d][i]   (verified)
// ---------------------------------------------------------------------------
__global__ __launch_bounds__(256) void k2_qk(const float* __restrict__ qT,
                                             const float* __restrict__ Wk,
                                             float* __restrict__ qkT) {
  const int h = blockIdx.y;
  const int it = blockIdx.x;
  const int il = threadIdx.x & 63;
  const int bs = __builtin_amdgcn_readfirstlane(threadIdx.x >> 6);
  const int i = it * 64 + il;
  const int boff = blockIdx.z * 64 + bs * 16;
  float acc[16];
#pragma unroll
  for (int k = 0; k < 16; k++) acc[k] = 0.f;
#pragma unroll 2
  for (int d = 0; d < DD; d++) {
    float wv = Wk[(size_t)(h * DD + d) * HH + i];
    const float* qrow = qT + (h * DD + d) * BB + boff;  // wave-uniform
#pragma unroll
    for (int k = 0; k < 16; k++) acc[k] = fmaf(qrow[k], wv, acc[k]);
  }
#pragma unroll
  for (int k = 0; k < 16; k++)
    qkT[(size_t)((boff + k) * NH + h) * HH + i] = SCALE * acc[k];
}

// ---------------------------------------------------------------------------
// K2b (verified R5): qkT[b][h][i] -> qkR[b][i>>2][16h][i&3].
// ---------------------------------------------------------------------------
__global__ __launch_bounds__(256) void k2b_relayout(
    const float* __restrict__ qkT, float* __restrict__ qkR) {
  __shared__ float lds[16][268];
  const int b = blockIdx.y, seg = blockIdx.x;
  const int t = threadIdx.x;
  const int row = t >> 4, l16 = t & 15;
  const float* src = qkT + (size_t)b * 16384 + row * HH + seg * 256 + l16 * 16;
#pragma unroll
  for (int p = 0; p < 4; p++)
    *(float4*)(&lds[row][l16 * 16 + p * 4]) = *(const float4*)(src + p * 4);
  __syncthreads();
  const int c = t & 63;    // h*4 + i3
  const int i4g = t >> 6;  // 0..3
  const int h = c >> 2, i3 = c & 3;
  float* dst = qkR + (size_t)b * 16384 + seg * 4096;
#pragma unroll
  for (int jj = 0; jj < 16; jj++) {
    const int i4l = i4g * 16 + jj;
    dst[i4l * 64 + c] = lds[h][i4l * 4 + i3];
  }
}

// ---------------------------------------------------------------------------
// K3a: scores[b][h][l] = mask ? NEG_BIG : sum_i key[b][l][i]*qk[b][h][i]
// grid (4 lt, 256 b), block 256 = 4 waves.  R9 compute/epilogue (verified
// numerics) with staging replaced by ZERO-VGPR global_load_lds:
//   key tile [64 rows][16 units] dbuf in LDS, XOR-swizzled: slot s of row r
//   holds logical unit s^(r&15).  Source-side swizzle (per-lane global addr),
//   LINEAR LDS dest (rule #21: both-sides-or-neither).  Read: slot=U^m15 ->
//   each bank-quad hit exactly 2x per 16 lanes = capacity-balanced.
//   qk chunk (4KB contiguous) staged linearly, layout unchanged vs R8/R9.
// Removes the kf[4]/qf staging registers that forced the compiler to spill
// acc once per chunk (R8: 167MB, R9: 515MB ghost HBM writes).
// ---------------------------------------------------------------------------
__global__ __launch_bounds__(256) void k3a_scores(
    const float* __restrict__ key, const int* __restrict__ mask,
    const float* __restrict__ qkR, float* __restrict__ scoresT) {
  __shared__ float kbuf[2][4096];  // [row 0..63][slot 0..15][4]
  __shared__ float qbuf[2][1024];  // [i4-unit 0..15][16h][i3]
  const int b = blockIdx.y;
  const int lt = blockIdx.x;
  const int t = threadIdx.x;
  const int g = __builtin_amdgcn_readfirstlane(t >> 6);  // h-quad
  const int ln = t & 63;
  const int m15 = ln & 15;  // row-group
  const int g4 = ln >> 4;   // i-quarter (K-split)

  const float* keyb = key + ((size_t)(b * LL + lt * 64)) * HH;
  const float* qkb = qkR + (size_t)b * 16384;

  // staging: thread t fills (row = t>>4 + 16p, slot = t&15) with logical
  // unit (t&15)^(t>>4); dest float offset = p*1024 + t*4  (linear in lane).
  const int srow = t >> 4;
  const int sunit = (t & 15) ^ srow;
  const float* ks0 = keyb + (size_t)(srow + 0) * HH + sunit * 4;
  const float* ks1 = keyb + (size_t)(srow + 16) * HH + sunit * 4;
  const float* ks2 = keyb + (size_t)(srow + 32) * HH + sunit * 4;
  const float* ks3 = keyb + (size_t)(srow + 48) * HH + sunit * 4;
  const float* qs = qkb + t * 4;

  gl_lds16(ks0, &kbuf[0][t * 4 + 0]);
  gl_lds16(ks1, &kbuf[0][t * 4 + 1024]);
  gl_lds16(ks2, &kbuf[0][t * 4 + 2048]);
  gl_lds16(ks3, &kbuf[0][t * 4 + 3072]);
  gl_lds16(qs, &qbuf[0][t * 4]);
  __syncthreads();

  float acc[4][4];
#pragma unroll
  for (int r = 0; r < 4; r++)
#pragma unroll
    for (int h = 0; h < 4; h++) acc[r][h] = 0.f;

  for (int c = 0; c < 16; c++) {
    if (c < 15) {
      const int nb = (c + 1) & 1;
      const int co = (c + 1) * 64;  // floats per chunk along i
      gl_lds16(ks0 + co, &kbuf[nb][t * 4 + 0]);
      gl_lds16(ks1 + co, &kbuf[nb][t * 4 + 1024]);
      gl_lds16(ks2 + co, &kbuf[nb][t * 4 + 2048]);
      gl_lds16(ks3 + co, &kbuf[nb][t * 4 + 3072]);
      gl_lds16(qs + (c + 1) * 1024, &qbuf[nb][t * 4]);
    }
    const float* kb = kbuf[c & 1];
    const float* qb = qbuf[c & 1];
#pragma unroll
    for (int iq = 0; iq < 4; iq++) {
      const int U = g4 * 4 + iq;                 // logical i-quad unit
      const float* qu = qb + U * 64 + g * 16;    // [4h][4i] fragment
      float4 q0 = *(const float4*)(qu + 0);
      float4 q1 = *(const float4*)(qu + 4);
      float4 q2 = *(const float4*)(qu + 8);
      float4 q3 = *(const float4*)(qu + 12);
      const int slot4 = (U ^ m15) * 4;           // read-side XOR (matches src)
#pragma unroll
      for (int r = 0; r < 4; r++) {
        float4 kv = *(const float4*)(kb + (m15 + 16 * r) * 64 + slot4);
        acc[r][0] = fmaf(kv.x, q0.x, acc[r][0]);
        acc[r][0] = fmaf(kv.y, q0.y, acc[r][0]);
        acc[r][0] = fmaf(kv.z, q0.z, acc[r][0]);
        acc[r][0] = fmaf(kv.w, q0.w, acc[r][0]);
        acc[r][1] = fmaf(kv.x, q1.x, acc[r][1]);
        acc[r][1] = fmaf(kv.y, q1.y, acc[r][1]);
        acc[r][1] = fmaf(kv.z, q1.z, acc[r][1]);
        acc[r][1] = fmaf(kv.w, q1.w, acc[r][1]);
        acc[r][2] = fmaf(kv.x, q2.x, acc[r][2]);
        acc[r][2] = fmaf(kv.y, q2.y, acc[r][2]);
        acc[r][2] = fmaf(kv.z, q2.z, acc[r][2]);
        acc[r][2] = fmaf(kv.w, q2.w, acc[r][2]);
        acc[r][3] = fmaf(kv.x, q3.x, acc[r][3]);
        acc[r][3] = fmaf(kv.y, q3.y, acc[r][3]);
        acc[r][3] = fmaf(kv.z, q3.z, acc[r][3]);
        acc[r][3] = fmaf(kv.w, q3.w, acc[r][3]);
      }
    }
    __syncthreads();  // drains vmcnt (next chunk in LDS) + read-WAR fence
  }

  // K-reduce across the 4 i-quarter lane groups (xor 16, 32)
#pragma unroll
  for (int r = 0; r < 4; r++)
#pragma unroll
    for (int h = 0; h < 4; h++) {
      acc[r][h] += __shfl_xor(acc[r][h], 16);
      acc[r][h] += __shfl_xor(acc[r][h], 32);
    }

  // lane group g4 outputs row-set r == g4 (static indices only, rule #20)
  float o0 = acc[0][0], o1 = acc[0][1], o2 = acc[0][2], o3 = acc[0][3];
  if (g4 == 1) { o0 = acc[1][0]; o1 = acc[1][1]; o2 = acc[1][2]; o3 = acc[1][3]; }
  if (g4 == 2) { o0 = acc[2][0]; o1 = acc[2][1]; o2 = acc[2][2]; o3 = acc[2][3]; }
  if (g4 == 3) { o0 = acc[3][0]; o1 = acc[3][1]; o2 = acc[3][2]; o3 = acc[3][3]; }

  const int l = lt * 64 + 16 * g4 + m15;
  const int mk = mask[b * LL + l];
  if (mk) { o0 = NEG_BIG; o1 = NEG_BIG; o2 = NEG_BIG; o3 = NEG_BIG; }
  scoresT[((size_t)(b * NH + g * 4 + 0)) * LL + l] = o0;
  scoresT[((size_t)(b * NH + g * 4 + 1)) * LL + l] = o1;
  scoresT[((size_t)(b * NH + g * 4 + 2)) * LL + l] = o2;
  scoresT[((size_t)(b * NH + g * 4 + 3)) * LL + l] = o3;
}

// ---------------------------------------------------------------------------
// K3b: in-place softmax over attn[(b*16+h)][256].   (verified)
// ---------------------------------------------------------------------------
__global__ __launch_bounds__(256) void k3b_softmax(float* __restrict__ attn) {
  const int r = blockIdx.x * 4 + (threadIdx.x >> 6);
  const int lane = threadIdx.x & 63;
  float* rowp = attn + (size_t)r * LL;
  float4 s = *(const float4*)(rowp + lane * 4);
  float m = fmaxf(fmaxf(s.x, s.y), fmaxf(s.z, s.w));
#pragma unroll
  for (int off = 32; off >= 1; off >>= 1) m = fmaxf(m, __shfl_xor(m, off));
  float ex = __expf(s.x - m), ey = __expf(s.y - m), ez = __expf(s.z - m),
        ew = __expf(s.w - m);
  float e = ex + ey + ez + ew;
#pragma unroll
  for (int off = 32; off >= 1; off >>= 1) e += __shfl_xor(e, off);
  float inv = 1.0f / e;
  *(float4*)(rowp + lane * 4) = make_float4(ex * inv, ey * inv, ez * inv, ew * inv);
}

// ---------------------------------------------------------------------------
// K3c: vbar[b][h][d] = sum_l attn[b][h][l] * value[b][l][d]   (verified R8/R9)
// ---------------------------------------------------------------------------
__global__ __launch_bounds__(256) void k3c_vbar(
    const float* __restrict__ value, const float* __restrict__ attn,
    float* __restrict__ vbar) {
  __shared__ float alds[4096];  // [16 h][256 l]
  const int b = blockIdx.y;
  const int dt = blockIdx.x;
  const int t = threadIdx.x;
  const int g = __builtin_amdgcn_readfirstlane(t >> 6);
  const int ln = t & 63;
  const float* ab = attn + (size_t)b * 4096;
#pragma unroll
  for (int j = 0; j < 4; j++)
    *(float4*)(alds + j * 1024 + t * 4) = *(const float4*)(ab + j * 1024 + t * 4);
  __syncthreads();

  const int d0 = dt * 256 + ln * 4;
  const float* valb = value + (size_t)b * LL * HH + d0;
  const float* aw = alds + g * 4 * 256;  // wave's 4 h rows

  float4 ac0 = make_float4(0.f, 0.f, 0.f, 0.f);
  float4 ac1 = ac0, ac2 = ac0, ac3 = ac0;

  float4 vf0 = *(const float4*)(valb + (size_t)0 * HH);
  float4 vf1 = *(const float4*)(valb + (size_t)1 * HH);
  float4 vf2 = *(const float4*)(valb + (size_t)2 * HH);
  float4 vf3 = *(const float4*)(valb + (size_t)3 * HH);

#pragma unroll 4
  for (int lq = 0; lq < 64; lq++) {
    float4 v0 = vf0, v1 = vf1, v2 = vf2, v3 = vf3;
    if (lq < 63) {
      vf0 = *(const float4*)(valb + (size_t)((lq + 1) * 4 + 0) * HH);
      vf1 = *(const float4*)(valb + (size_t)((lq + 1) * 4 + 1) * HH);
      vf2 = *(const float4*)(valb + (size_t)((lq + 1) * 4 + 2) * HH);
      vf3 = *(const float4*)(valb + (size_t)((lq + 1) * 4 + 3) * HH);
    }
    float4 a0 = *(const float4*)(aw + 0 * 256 + lq * 4);
    float4 a1 = *(const float4*)(aw + 1 * 256 + lq * 4);
    float4 a2 = *(const float4*)(aw + 2 * 256 + lq * 4);
    float4 a3 = *(const float4*)(aw + 3 * 256 + lq * 4);
    FMA4(ac0, v0, a0.x); FMA4(ac0, v1, a0.y); FMA4(ac0, v2, a0.z); FMA4(ac0, v3, a0.w);
    FMA4(ac1, v0, a1.x); FMA4(ac1, v1, a1.y); FMA4(ac1, v2, a1.z); FMA4(ac1, v3, a1.w);
    FMA4(ac2, v0, a2.x); FMA4(ac2, v1, a2.y); FMA4(ac2, v2, a2.z); FMA4(ac2, v3, a2.w);
    FMA4(ac3, v0, a3.x); FMA4(ac3, v1, a3.y); FMA4(ac3, v2, a3.z); FMA4(ac3, v3, a3.w);
  }
  float* vb = vbar + ((size_t)(b * NH + g * 4)) * HH + d0;
  *(float4*)(vb + 0 * HH) = ac0;
  *(float4*)(vb + 1 * HH) = ac1;
  *(float4*)(vb + 2 * HH) = ac2;
  *(float4*)(vb + 3 * HH) = ac3;
}

// ---------------------------------------------------------------------------
// K4: ctxT[j][b] = bv[j] + sum_i vbar[b][j>>6][i] * Wv[j][i]   (verified)
// ---------------------------------------------------------------------------
__global__ __launch_bounds__(256) void k4_ctx(const float* __restrict__ Wv,
                                              const float* __restrict__ vbarT,
                                              const float* __restrict__ bv,
                                              float* __restrict__ ctxT) {
  __shared__ float smem[10240];
  const int jt = blockIdx.x;
  const int boff = blockIdx.y * 8;
  const int t = threadIdx.x;
  const int g = __builtin_amdgcn_readfirstlane(t >> 6);
  const int ln = t & 63;
  float* kw = smem + g * 2560;
  const float* Wb = Wv + (size_t)(jt * 64) * HH;
  const float* vt = vbarT + (size_t)jt * HH * BB;
  const int srow = ln >> 2, sc = ln & 3;

  float acc[8];
#pragma unroll
  for (int c = 0; c < 8; c++) acc[c] = 0.f;
  float4 pf[4];
#pragma unroll
  for (int p = 0; p < 4; p++)
    pf[p] = *(const float4*)(Wb + (size_t)(p * 16 + srow) * HH + g * 16 + sc * 4);
  int buf = 0;
  for (int T = 0; T < 16; T++) {
    float* kb = kw + buf * 1280;
#pragma unroll
    for (int p = 0; p < 4; p++)
      *(float4*)(kb + ((p * 16 + srow) * 5 + sc) * 4) = pf[p];
    if (T < 15) {
      const int off = (T + 1) * 64 + g * 16 + sc * 4;
#pragma unroll
      for (int p = 0; p < 4; p++)
        pf[p] = *(const float4*)(Wb + (size_t)(p * 16 + srow) * HH + off);
    }
    const int i0 = T * 64 + g * 16;
#pragma unroll
    for (int u = 0; u < 4; u++) {
      float4 kv = *(const float4*)(kb + (ln * 5 + u) * 4);
      const float* q0 = vt + (size_t)(i0 + u * 4 + 0) * BB + boff;
      const float* q1 = vt + (size_t)(i0 + u * 4 + 1) * BB + boff;
      const float* q2 = vt + (size_t)(i0 + u * 4 + 2) * BB + boff;
      const float* q3 = vt + (size_t)(i0 + u * 4 + 3) * BB + boff;
#pragma unroll
      for (int c = 0; c < 8; c++) {
        acc[c] = fmaf(kv.x, q0[c], acc[c]);
        acc[c] = fmaf(kv.y, q1[c], acc[c]);
        acc[c] = fmaf(kv.z, q2[c], acc[c]);
        acc[c] = fmaf(kv.w, q3[c], acc[c]);
      }
    }
    buf ^= 1;
  }
  __syncthreads();
  float* part = smem;
  *(float4*)(part + g * 768 + ln * 12 + 0) =
      make_float4(acc[0], acc[1], acc[2], acc[3]);
  *(float4*)(part + g * 768 + ln * 12 + 4) =
      make_float4(acc[4], acc[5], acc[6], acc[7]);
  __syncthreads();
  const int j = t & 63, c0 = (t >> 6) * 2;
  float v0 = 0.f, v1 = 0.f;
#pragma unroll
  for (int g2 = 0; g2 < 4; g2++) {
    v0 += part[g2 * 768 + j * 12 + c0];
    v1 += part[g2 * 768 + j * 12 + c0 + 1];
  }
  const int jg = jt * 64 + j;
  const float bias = bv[jg];
  *(float2*)(ctxT + (size_t)jg * BB + boff + c0) =
      make_float2(v0 + bias, v1 + bias);
}

// ---------------------------------------------------------------------------
// K5: xws[b][j] = query[b][j] + bf[j] + sum_i ctxT[i][b] * Wf[j][i]  (verified)
// ---------------------------------------------------------------------------
__global__ __launch_bounds__(256) void k5_outproj(
    const float* __restrict__ Wf, const float* __restrict__ ctxT,
    const float* __restrict__ bf, const float* __restrict__ query,
    float* __restrict__ xws) {
  __shared__ float smem[10240];
  const int jt = blockIdx.x;
  const int boff = blockIdx.y * 8;
  const int t = threadIdx.x;
  const int g = __builtin_amdgcn_readfirstlane(t >> 6);
  const int ln = t & 63;
  float* kw = smem + g * 2560;
  const float* Wb = Wf + (size_t)(jt * 64) * HH;
  const int srow = ln >> 2, sc = ln & 3;

  float acc[8];
#pragma unroll
  for (int c = 0; c < 8; c++) acc[c] = 0.f;
  float4 pf[4];
#pragma unroll
  for (int p = 0; p < 4; p++)
    pf[p] = *(const float4*)(Wb + (size_t)(p * 16 + srow) * HH + g * 16 + sc * 4);
  int buf = 0;
  for (int T = 0; T < 16; T++) {
    float* kb = kw + buf * 1280;
#pragma unroll
    for (int p = 0; p < 4; p++)
      *(float4*)(kb + ((p * 16 + srow) * 5 + sc) * 4) = pf[p];
    if (T < 15) {
      const int off = (T + 1) * 64 + g * 16 + sc * 4;
#pragma unroll
      for (int p = 0; p < 4; p++)
        pf[p] = *(const float4*)(Wb + (size_t)(p * 16 + srow) * HH + off);
    }
    const int i0 = T * 64 + g * 16;
#pragma unroll
    for (int u = 0; u < 4; u++) {
      float4 kv = *(const float4*)(kb + (ln * 5 + u) * 4);
      const float* q0 = ctxT + (size_t)(i0 + u * 4 + 0) * BB + boff;
      const float* q1 = ctxT + (size_t)(i0 + u * 4 + 1) * BB + boff;
      const float* q2 = ctxT + (size_t)(i0 + u * 4 + 2) * BB + boff;
      const float* q3 = ctxT + (size_t)(i0 + u * 4 + 3) * BB + boff;
#pragma unroll
      for (int c = 0; c < 8; c++) {
        acc[c] = fmaf(kv.x, q0[c], acc[c]);
        acc[c] = fmaf(kv.y, q1[c], acc[c]);
        acc[c] = fmaf(kv.z, q2[c], acc[c]);
        acc[c] = fmaf(kv.w, q3[c], acc[c]);
      }
    }
    buf ^= 1;
  }
  __syncthreads();
  float* part = smem;
  *(float4*)(part + g * 768 + ln * 12 + 0) =
      make_float4(acc[0], acc[1], acc[2], acc[3]);
  *(float4*)(part + g * 768 + ln * 12 + 4) =
      make_float4(acc[4], acc[5], acc[6], acc[7]);
  __syncthreads();
  const int j = t & 63, c0 = (t >> 6) * 2;
  float v0 = 0.f, v1 = 0.f;
#pragma unroll
  for (int g2 = 0; g2 < 4; g2++) {
    v0 += part[g2 * 768 + j * 12 + c0];
    v1 += part[g2 * 768 + j * 12 + c0 + 1];
  }
  const int jg = jt * 64 + j;
  const float bias = bf[jg];
  const int b0 = boff + c0;
  xws[(size_t)b0 * HH + jg] = v0 + bias + query[(size_t)b0 * HH + jg];
  xws[(size_t)(b0 + 1) * HH + jg] = v1 + bias + query[(size_t)(b0 + 1) * HH + jg];
}

// ---------------------------------------------------------------------------
// K6: LayerNorm over H, two-pass (exact), block per b.   (verified)
// ---------------------------------------------------------------------------
__global__ __launch_bounds__(256) void k6_ln(const float* __restrict__ xws,
                                             const float* __restrict__ gamma,
                                             const float* __restrict__ beta,
                                             float* __restrict__ out0) {
  __shared__ float rb[8];
  const int b = blockIdx.x, t = threadIdx.x;
  float4 v = *(const float4*)(xws + (size_t)b * HH + 4 * t);
  float s = v.x + v.y + v.z + v.w;
#pragma unroll
  for (int off = 32; off >= 1; off >>= 1) s += __shfl_xor(s, off);
  if ((t & 63) == 0) rb[t >> 6] = s;
  __syncthreads();
  float mu = (rb[0] + rb[1] + rb[2] + rb[3]) * (1.0f / HH);
  float dx = v.x - mu, dy = v.y - mu, dz = v.z - mu, dw = v.w - mu;
  float q = dx * dx + dy * dy + dz * dz + dw * dw;
#pragma unroll
  for (int off = 32; off >= 1; off >>= 1) q += __shfl_xor(q, off);
  if ((t & 63) == 0) rb[4 + (t >> 6)] = q;
  __syncthreads();
  float var = (rb[4] + rb[5] + rb[6] + rb[7]) * (1.0f / HH);
  float rs = rsqrtf(var + LN_EPS);
  float4 gm = *(const float4*)(gamma + 4 * t);
  float4 bt = *(const float4*)(beta + 4 * t);
  float4 o;
  o.x = dx * rs * gm.x + bt.x;
  o.y = dy * rs * gm.y + bt.y;
  o.z = dz * rs * gm.z + bt.z;
  o.w = dw * rs * gm.w + bt.w;
  *(float4*)(out0 + (size_t)b * HH + 4 * t) = o;
}

extern "C" void kernel_launch(void* const* d_in, const int* in_sizes, int n_in,
                              void* d_out, int out_size, void* d_ws,
                              size_t ws_size, hipStream_t stream) {
  (void)in_sizes; (void)n_in; (void)out_size; (void)ws_size;
  const float* key = (const float*)d_in[0];
  const float* value = (const float*)d_in[1];
  const float* query = (const float*)d_in[2];
  const int* mask = (const int*)d_in[3];
  const float* Wq = (const float*)d_in[4];
  const float* bq = (const float*)d_in[5];
  const float* Wk = (const float*)d_in[6];
  // d_in[7] = bk: softmax-invariant, dropped
  const float* Wv = (const float*)d_in[8];
  const float* bv = (const float*)d_in[9];
  const float* Wf = (const float*)d_in[10];
  const float* bf = (const float*)d_in[11];
  const float* gamma = (const float*)d_in[12];
  const float* beta = (const float*)d_in[13];

  float* out0 = (float*)d_out;      // (B,1,H)
  float* attnOut = out0 + BB * HH;  // (B*NH,1,L): scores -> softmax in place

  // ws lifetimes: qT dead after k2 (ctxT reuses); qTT dead after k1 (xws
  // reuses); qkT dead after k2b (vbar reuses); qkR dead after k3a.
  char* ws = (char*)d_ws;
  float* qT = (float*)(ws);                  //  1 MB [j][b]
  float* qTT = (float*)(ws + (1 << 20));     //  1 MB [i][b]
  float* qkT = (float*)(ws + (2 << 20));     // 16 MB [b][h][i]
  float* qkR = (float*)(ws + (18 << 20));    // 16 MB [b][i4][16h][i3]
  float* vbar = (float*)(ws + (2 << 20));    // 16 MB [b][h][i] (over qkT)
  float* vbarT = (float*)(ws + (34 << 20));  // 16 MB [h][i][b]
  float* ctxT = (float*)(ws);                //  1 MB [j][b]   (over qT)
  float* xws = (float*)(ws + (1 << 20));     //  1 MB [b][j]   (over qTT)

  t_tr<<<dim3(16, 4, 1), 256, 0, stream>>>(query, qTT, HH, BB, 0, 0);
  k1_qproj<<<dim3(16, 32), 256, 0, stream>>>(Wq, qTT, bq, qT);
  k2_qk<<<dim3(16, 16, 4), 256, 0, stream>>>(qT, Wk, qkT);
  k2b_relayout<<<dim3(4, 256), 256, 0, stream>>>(qkT, qkR);
  k3a_scores<<<dim3(4, 256), 256, 0, stream>>>(key, mask, qkR, attnOut);
  k3b_softmax<<<dim3(1024), 256, 0, stream>>>(attnOut);
  k3c_vbar<<<dim3(4, 256), 256, 0, stream>>>(value, attnOut, vbar);
  t_tr<<<dim3(16, 4, 16), 256, 0, stream>>>(vbar, vbarT, NH * HH, BB, HH,
                                            HH * BB);
  k4_ctx<<<dim3(16, 32), 256, 0, stream>>>(Wv, vbarT, bv, ctxT);
  k5_outproj<<<dim3(16, 32), 256, 0, stream>>>(Wf, ctxT, bf, query, xws);
  k6_ln<<<dim3(256), 256, 0, stream>>>(xws, gamma, beta, out0);
}